// Round 1
// baseline (598.316 us; speedup 1.0000x reference)
//
#include <hip/hip_runtime.h>
#include <stdint.h>

// ---------------- problem constants (DSVT-Pillar, Waymo single stage) ----------
// sparse shape 468x468x1; windows 12x12x1 (shift 0,0) and 24x24x1 (shift 6,6)
// set size 36; dim 192; 8 pos-embed heads (4 blocks x 2 shifts)
#define DIM 192
#define SET_SIZE 36

// shift 0: mx=my=40, mz=2 -> id = b*3200 + (x/12)*80 + (y/12)*2 + z ; max id < 6400
#define W0 6400
#define MV0 144
// shift 1: mx=my=21, mz=2 -> id = b*882 + ((x+6)/24)*42 + ((y+6)/24)*2 + z ; max id < 1764
#define W1 1764
#define MV1 576

#define CAP_S0 6144   // worst case sets shift0 ~4709
#define CAP_S1 4096   // worst case sets shift1 ~2467

// ---------------- workspace layout (int units) — unchanged from prev round -----
#define OFF_CNT0     0            // 6400
#define OFF_CNT1     6400         // 1764
#define OFF_MOM      8164         // 10 (Sx0,Sy0,Sxx0,Syy0,Sxy0, Sx1,Sy1,Sxx1,Syy1,Sxy1)
#define OFF_S0       8174
#define OFF_S1       8175
#define OFF_ZERO_END 8176
#define OFF_SETBASE0 8192         // 6400
#define OFF_SETBASE1 14592        // 1764
#define OFF_SETWIN0  16356        // (unused now, kept for layout stability)
#define OFF_SETWIN1  22500
#define OFF_CELL0    26596        // 60000
#define OFF_CELL1    86596        // 60000
#define OFF_SLOTY0   146596       // 6400*144 = 921600
#define OFF_SLOTX0   1068196      // 921600
#define OFF_SLOTY1   1989796      // 1764*576 = 1016064
#define OFF_SLOTX1   3005860      // 1016064
#define OFF_TABLE    4021924      // 8*576*192 floats = 884736
#define WS_TOTAL     4906660      // ints (~18.7 MiB)

// ---------------- kernel 1: per-voxel pass -------------------------------------
// window ids, slot scatter (y-major & x-major), cell ids, integer moments of (xx,yy)
__global__ void voxel_pass(const int4* __restrict__ coords, int N, int* __restrict__ ws) {
    int v = blockIdx.x * blockDim.x + threadIdx.x;
    int xx0 = 0, yy0 = 0, xx1 = 0, yy1 = 0;
    if (v < N) {
        int4 c = coords[v];
        int b = c.x, z = c.y, y = c.z, x = c.w;
        // shift 0
        int xin0 = x % 12, yin0 = y % 12;
        int w0 = b * 3200 + (x / 12) * 80 + (y / 12) * 2 + z;
        atomicAdd(&ws[OFF_CNT0 + w0], 1);
        ws[OFF_SLOTY0 + w0 * MV0 + yin0 * 12 + xin0] = v;
        ws[OFF_SLOTX0 + w0 * MV0 + xin0 * 12 + yin0] = v;
        ws[OFF_CELL0 + v] = yin0 * 12 + xin0;
        // shift 1
        int sx = x + 6, sy = y + 6;
        int xin1 = sx % 24, yin1 = sy % 24;
        int w1 = b * 882 + (sx / 24) * 42 + (sy / 24) * 2 + z;
        atomicAdd(&ws[OFF_CNT1 + w1], 1);
        ws[OFF_SLOTY1 + w1 * MV1 + yin1 * 24 + xin1] = v;
        ws[OFF_SLOTX1 + w1 * MV1 + xin1 * 24 + yin1] = v;
        ws[OFF_CELL1 + v] = yin1 * 24 + xin1;
        // pos-embed locations use base window half-extent (6) for BOTH shifts
        xx0 = xin0 - 6; yy0 = yin0 - 6;
        xx1 = xin1 - 6; yy1 = yin1 - 6;
    }
    // wave-level shuffle reduction of the 10 integer moments; 1 global atomic/wave each
    int mvals[10] = {xx0, yy0, xx0 * xx0, yy0 * yy0, xx0 * yy0,
                     xx1, yy1, xx1 * xx1, yy1 * yy1, xx1 * yy1};
    #pragma unroll
    for (int m = 0; m < 10; m++) {
        int s = mvals[m];
        #pragma unroll
        for (int off = 32; off > 0; off >>= 1) s += __shfl_down(s, off);  // wave64
        if ((threadIdx.x & 63) == 0) atomicAdd(&ws[OFF_MOM + m], s);
    }
}

// ---------------- kernel 2: both scans in one launch (block 0 = shift0) --------
// setnum = ceil(cnt/36); exclusive scan -> setBase; S total. setWin no longer needed.
__global__ void scan_both(int* __restrict__ ws) {
    __shared__ int sm[256];
    int shift = blockIdx.x;
    const int W = shift ? W1 : W0;
    const int cap = shift ? CAP_S1 : CAP_S0;
    const int* cnt = ws + (shift ? OFF_CNT1 : OFF_CNT0);
    int* setBase = ws + (shift ? OFF_SETBASE1 : OFF_SETBASE0);
    int* S_out   = ws + (shift ? OFF_S1 : OFF_S0);
    int tid = threadIdx.x;
    int chunk = (W + 255) >> 8;
    int lo = tid * chunk;
    int hi = lo + chunk; if (hi > W) hi = W; if (lo > W) lo = W;
    int local = 0;
    for (int w = lo; w < hi; w++) local += (cnt[w] + SET_SIZE - 1) / SET_SIZE;
    sm[tid] = local;
    __syncthreads();
    for (int off = 1; off < 256; off <<= 1) {
        int t = (tid >= off) ? sm[tid - off] : 0;
        __syncthreads();
        sm[tid] += t;
        __syncthreads();
    }
    int base = sm[tid] - local;   // exclusive prefix
    if (tid == 255) {
        int S = sm[255];
        if (S > cap) S = cap;     // safety clamp (should never trigger)
        *S_out = S;
    }
    for (int w = lo; w < hi; w++) setBase[w] = (base += 0, base), base += (cnt[w] + SET_SIZE - 1) / SET_SIZE;
}

// ---------------- kernel 3: fused compact (to LDS) + set/mask emit -------------
// one block per window (both shifts); wave0 compacts Y-order, wave1 X-order;
// then all 128 threads emit that window's sets + masks directly to the output.
__global__ void __launch_bounds__(128)
compact_write(const int* __restrict__ ws, float* __restrict__ outArea) {
    __shared__ int sY[MV1], sX[MV1];
    int bw = blockIdx.x;
    int shift = (bw >= W0) ? 1 : 0;
    int w = shift ? (bw - W0) : bw;
    int cnt = ws[(shift ? OFF_CNT1 : OFF_CNT0) + w];
    if (cnt == 0) return;                       // block-uniform
    int MV = shift ? MV1 : MV0;
    const int* slotY = ws + (shift ? OFF_SLOTY1 : OFF_SLOTY0) + (size_t)w * MV;
    const int* slotX = ws + (shift ? OFF_SLOTX1 : OFF_SLOTX0) + (size_t)w * MV;
    int lane = threadIdx.x & 63;
    int wsel = threadIdx.x >> 6;                // wave 0 -> Y, wave 1 -> X
    {
        const int* slot = wsel ? slotX : slotY;
        int* dst = wsel ? sX : sY;
        int base = 0;
        for (int p0 = 0; p0 < MV; p0 += 64) {
            int p = p0 + lane;
            int v = (p < MV) ? slot[p] : -1;
            bool occ = v >= 0;
            unsigned long long m = __ballot(occ);
            int rank = __popcll(m & ((1ull << lane) - 1ull));
            if (occ) dst[base + rank] = v;
            base += __popcll(m);
        }
    }
    __syncthreads();
    int S = ws[shift ? OFF_S1 : OFF_S0];
    long long sOff = shift ? 4LL * SET_SIZE * (long long)ws[OFF_S0] : 0;
    int sb = ws[(shift ? OFF_SETBASE1 : OFF_SETBASE0) + w];
    int setnum = (cnt + SET_SIZE - 1) / SET_SIZE;
    int den = setnum * SET_SIZE;
    int total = 2 * den;                        // 2 branches x setnum x 36
    for (int e = threadIdx.x; e < total; e += 128) {
        int branch = (e >= den) ? 1 : 0;
        int rem = e - branch * den;             // = i*36 + j
        int i = rem / 36, j = rem - i * 36;
        int q = sb + i;
        if (q >= S) continue;                   // only possible if clamp fired
        int r  = (rem * cnt) / den;             // DSVT Eq.3 spreading
        int rp = (j > 0) ? (((rem - 1) * cnt) / den) : -1;
        int vox = branch ? sX[r] : sY[r];
        long long idx = (long long)branch * S * SET_SIZE + (long long)q * SET_SIZE + j;
        outArea[sOff + idx] = (float)vox;                                   // set_inds
        outArea[sOff + 2LL * S * SET_SIZE + idx] = (r == rp) ? 1.0f : 0.0f; // mask
    }
}

// ---------------- kernel 4: pos-embed lookup table, 8 cells per block ----------
// reuses each w2 column load across 8 cells (L2 traffic /8 vs per-cell blocks)
__global__ void __launch_bounds__(192)
build_table(const float* __restrict__ w1, const float* __restrict__ gamma,
            const float* __restrict__ beta, const float* __restrict__ w2,
            const float* __restrict__ b2, const int* __restrict__ mom,
            float* __restrict__ table, int N) {
    // grid: 4 even-k heads * 18 tiles (wdim=12, 144 cells), then 4 odd * 72 (wdim=24)
    int bid = blockIdx.x;
    int k, tile, wdim;
    if (bid < 72) { k = (bid / 18) * 2;            tile = bid % 18; wdim = 12; }
    else { int b = bid - 72; k = (b / 72) * 2 + 1; tile = b % 72;   wdim = 24; }
    int shift = k & 1;
    int j = threadIdx.x;
    const int* m = mom + shift * 5;
    double invN = 1.0 / (double)N;
    double mx = m[0] * invN, my = m[1] * invN;
    double vx = m[2] * invN - mx * mx;
    double vy = m[3] * invN - my * my;
    double cxy = m[4] * invN - mx * my;
    float w10 = w1[(k * 2 + 0) * DIM + j];
    float w11 = w1[(k * 2 + 1) * DIM + j];
    double var = (double)w10 * w10 * vx + (double)w11 * w11 * vy + 2.0 * (double)w10 * w11 * cxy;
    double rs = 1.0 / sqrt(var + 1e-5);
    double gs = rs * (double)gamma[k * DIM + j];
    double bt = (double)beta[k * DIM + j];
    __shared__ float sh[8][DIM];
    #pragma unroll
    for (int c = 0; c < 8; c++) {
        int cell = tile * 8 + c;
        int cy = cell / wdim, cx = cell - cy * wdim;
        double hn = (((double)(cx - 6) - mx) * (double)w10 +
                     ((double)(cy - 6) - my) * (double)w11) * gs + bt;
        sh[c][j] = hn > 0.0 ? (float)hn : 0.0f;   // ReLU
    }
    __syncthreads();
    float acc[8];
    float bb = b2[k * DIM + j];
    #pragma unroll
    for (int c = 0; c < 8; c++) acc[c] = bb;
    const float* w2k = w2 + (size_t)k * DIM * DIM;
    for (int i = 0; i < DIM; i++) {
        float wv = w2k[i * DIM + j];
        #pragma unroll
        for (int c = 0; c < 8; c++) acc[c] = fmaf(sh[c][i], wv, acc[c]);
    }
    #pragma unroll
    for (int c = 0; c < 8; c++)
        table[((size_t)k * MV1 + tile * 8 + c) * DIM + j] = acc[c];
}

// ---------------- kernel 5: mega output writer --------------------------------
// grid (ceil(N*48/256), 9): y<8 -> pos-embed scatter for head y; y==8 -> feat copy
// (N*48 float4 too) and coords int4->float4 piggybacked on the first N threads.
__global__ void write_out(const float4* __restrict__ table, const int* __restrict__ cell0,
                          const int* __restrict__ cell1, const float4* __restrict__ feat,
                          const int4* __restrict__ coords, float4* __restrict__ outPe,
                          float4* __restrict__ outFeat, float4* __restrict__ outCoords,
                          int N) {
    int t = blockIdx.x * 256 + threadIdx.x;
    if (t >= N * 48) return;
    int k = blockIdx.y;
    if (k < 8) {
        int v = t / 48;
        int q = t - v * 48;
        int cell = (k & 1) ? cell1[v] : cell0[v];
        outPe[(size_t)k * N * 48 + t] = table[((size_t)k * MV1 + cell) * 48 + q];
    } else {
        outFeat[t] = feat[t];
        if (t < N) {
            int4 c = coords[t];
            outCoords[t] = make_float4((float)c.x, (float)c.y, (float)c.z, (float)c.w);
        }
    }
}

extern "C" void kernel_launch(void* const* d_in, const int* in_sizes, int n_in,
                              void* d_out, int out_size, void* d_ws, size_t ws_size,
                              hipStream_t stream) {
    const float* feat  = (const float*)d_in[0];
    const int* coords  = (const int*)d_in[1];
    const float* w1    = (const float*)d_in[2];
    // d_in[3] = pe_b1: cancels inside BN (h - mu), unused
    const float* gamma = (const float*)d_in[4];
    const float* beta  = (const float*)d_in[5];
    const float* w2    = (const float*)d_in[6];
    const float* b2    = (const float*)d_in[7];
    int N = in_sizes[1] / 4;   // 60000
    int* ws = (int*)d_ws;
    float* out = (float*)d_out;

    // init workspace (ws is poisoned 0xAA before every launch)
    hipMemsetAsync(ws, 0, (size_t)OFF_ZERO_END * sizeof(int), stream);
    hipMemsetAsync(ws + OFF_SLOTY0, 0xFF, (size_t)(OFF_TABLE - OFF_SLOTY0) * sizeof(int), stream);

    voxel_pass<<<(N + 255) / 256, 256, 0, stream>>>((const int4*)coords, N, ws);

    scan_both<<<2, 256, 0, stream>>>(ws);

    // output layout (floats): [feat N*192][coords N*4][inds0 2*S0*36][mask0 2*S0*36]
    //                         [inds1 2*S1*36][mask1 2*S1*36][pos_embeds 8*N*192]
    long long off2 = (long long)N * DIM + (long long)N * 4;
    compact_write<<<W0 + W1, 128, 0, stream>>>(ws, out + off2);

    build_table<<<4 * 18 + 4 * 72, DIM, 0, stream>>>(w1, gamma, beta, w2, b2,
                                                     ws + OFF_MOM, (float*)(ws + OFF_TABLE), N);

    long long off6 = (long long)out_size - 8LL * N * DIM;
    dim3 g((unsigned)((N * 48 + 255) / 256), 9);
    write_out<<<g, 256, 0, stream>>>((const float4*)(ws + OFF_TABLE),
                                     ws + OFF_CELL0, ws + OFF_CELL1,
                                     (const float4*)feat, (const int4*)coords,
                                     (float4*)(out + off6), (float4*)out,
                                     (float4*)(out + (long long)N * DIM), N);
}

// Round 2
// 520.523 us; speedup vs baseline: 1.1495x; 1.1495x over previous
//
#include <hip/hip_runtime.h>
#include <stdint.h>

// ---------------- problem constants (DSVT-Pillar, Waymo single stage) ----------
// sparse shape 468x468x1; windows 12x12x1 (shift 0,0) and 24x24x1 (shift 6,6)
// set size 36; dim 192; 8 pos-embed heads (4 blocks x 2 shifts)
// NOTE: z == 0 for every voxel (pillars). Reference window id = b*3200 +
// (x/12)*80 + (y/12)*2 + z  ==  2 * (b*1600 + (x/12)*40 + (y/12)).  The map is
// monotone, so grouping AND window ordering are preserved with half the ids.
#define DIM 192
#define SET_SIZE 36

#define W0 3200           // shift 0 windows (b*1600 + wx*40 + wy)
#define MV0 144
#define W1 882            // shift 1 windows (b*441 + wx*21 + wy)
#define MV1 576

#define CAP_S0 6144
#define CAP_S1 4096

// ---------------- workspace layout (int units) ---------------------------------
#define OFF_CNT0     0            // 3200
#define OFF_CNT1     3200         // 882
#define OFF_MOM      4082         // 10 (Sx0,Sy0,Sxx0,Syy0,Sxy0, Sx1,Sy1,Sxx1,Syy1,Sxy1)
#define OFF_S0       4092
#define OFF_S1       4093
#define OFF_ZERO_END 4096
#define OFF_SETBASE0 4096         // 3200
#define OFF_SETBASE1 7296         // 882 (ends 8178)
#define OFF_SETWIN0  8192         // 6144
#define OFF_SETWIN1  14336        // 4096
#define OFF_CELL0    18432        // 60000
#define OFF_CELL1    78432        // 60000
#define OFF_SLOTY0   138432       // 3200*144 = 460800
#define OFF_SLOTX0   599232       // 460800
#define OFF_SLOTY1   1060032      // 882*576 = 508032
#define OFF_SLOTX1   1568064      // 508032
#define OFF_TABLE    2076096      // 8*576*192 floats = 884736
#define WS_TOTAL     2960832      // ints (~11.3 MiB)

#define SLOT4 ((OFF_TABLE - OFF_SLOTY0) / 4)   // 484416 int4 of 0xFF fill

// ---------------- kernel 0: workspace init (replaces two memsets) --------------
__global__ void init_ws(int* __restrict__ ws) {
    int t = blockIdx.x * 256 + threadIdx.x;
    if (t < OFF_ZERO_END / 4) ((int4*)ws)[t] = make_int4(0, 0, 0, 0);
    if (t < SLOT4) ((int4*)(ws + OFF_SLOTY0))[t] = make_int4(-1, -1, -1, -1);
}

// ---------------- kernel 1: per-voxel pass (round-0 body, halved ids) ----------
__global__ void voxel_pass(const int4* __restrict__ coords, int N, int* __restrict__ ws) {
    int v = blockIdx.x * blockDim.x + threadIdx.x;
    __shared__ int sm[10];
    if (threadIdx.x < 10) sm[threadIdx.x] = 0;
    __syncthreads();
    if (v < N) {
        int4 c = coords[v];
        int b = c.x, y = c.z, x = c.w;   // c.y == z == 0 always
        // shift 0
        int xin0 = x % 12, yin0 = y % 12;
        int w0 = b * 1600 + (x / 12) * 40 + (y / 12);
        atomicAdd(&ws[OFF_CNT0 + w0], 1);
        ws[OFF_SLOTY0 + w0 * MV0 + yin0 * 12 + xin0] = v;
        ws[OFF_SLOTX0 + w0 * MV0 + xin0 * 12 + yin0] = v;
        ws[OFF_CELL0 + v] = yin0 * 12 + xin0;
        // shift 1
        int sx = x + 6, sy = y + 6;
        int xin1 = sx % 24, yin1 = sy % 24;
        int w1 = b * 441 + (sx / 24) * 21 + (sy / 24);
        atomicAdd(&ws[OFF_CNT1 + w1], 1);
        ws[OFF_SLOTY1 + w1 * MV1 + yin1 * 24 + xin1] = v;
        ws[OFF_SLOTX1 + w1 * MV1 + xin1 * 24 + yin1] = v;
        ws[OFF_CELL1 + v] = yin1 * 24 + xin1;
        // integer moments (pos-embed BN stats; base-window half-extent 6 for BOTH shifts)
        int xx0 = xin0 - 6, yy0 = yin0 - 6;
        int xx1 = xin1 - 6, yy1 = yin1 - 6;
        atomicAdd(&sm[0], xx0); atomicAdd(&sm[1], yy0);
        atomicAdd(&sm[2], xx0 * xx0); atomicAdd(&sm[3], yy0 * yy0); atomicAdd(&sm[4], xx0 * yy0);
        atomicAdd(&sm[5], xx1); atomicAdd(&sm[6], yy1);
        atomicAdd(&sm[7], xx1 * xx1); atomicAdd(&sm[8], yy1 * yy1); atomicAdd(&sm[9], xx1 * yy1);
    }
    __syncthreads();
    if (threadIdx.x < 10) atomicAdd(&ws[OFF_MOM + threadIdx.x], sm[threadIdx.x]);
}

// ---------------- kernel 2: both scans, one launch (round-0 body) --------------
__global__ void scan_both(int* __restrict__ ws) {
    __shared__ int sm[256];
    int shift = blockIdx.x;
    const int W = shift ? W1 : W0;
    const int cap = shift ? CAP_S1 : CAP_S0;
    const int* cnt = ws + (shift ? OFF_CNT1 : OFF_CNT0);
    int* setBase = ws + (shift ? OFF_SETBASE1 : OFF_SETBASE0);
    int* setWin  = ws + (shift ? OFF_SETWIN1 : OFF_SETWIN0);
    int* S_out   = ws + (shift ? OFF_S1 : OFF_S0);
    int tid = threadIdx.x;
    int chunk = (W + 255) >> 8;
    int lo = tid * chunk;
    int hi = lo + chunk; if (hi > W) hi = W; if (lo > W) lo = W;
    int local = 0;
    for (int w = lo; w < hi; w++) local += (cnt[w] + SET_SIZE - 1) / SET_SIZE;
    sm[tid] = local;
    __syncthreads();
    for (int off = 1; off < 256; off <<= 1) {
        int t = (tid >= off) ? sm[tid - off] : 0;
        __syncthreads();
        sm[tid] += t;
        __syncthreads();
    }
    int base = sm[tid] - local;   // exclusive prefix
    if (tid == 255) {
        int S = sm[255];
        if (S > cap) S = cap;     // safety clamp (should never trigger)
        *S_out = S;
    }
    for (int w = lo; w < hi; w++) {
        setBase[w] = base;
        int sn = (cnt[w] + SET_SIZE - 1) / SET_SIZE;
        for (int s = 0; s < sn; s++) {
            int idx = base + s;
            if (idx < cap) setWin[idx] = w;
        }
        base += sn;
    }
}

// ---------------- kernel 3: in-place slot compaction (round-0 body, merged) ----
__global__ void compact_all(int* __restrict__ ws) {
    int bw = blockIdx.x;
    int shift = (bw >= W0) ? 1 : 0;
    int w = shift ? (bw - W0) : bw;
    int MV = shift ? MV1 : MV0;
    int* slotY = ws + (shift ? OFF_SLOTY1 : OFF_SLOTY0);
    int* slotX = ws + (shift ? OFF_SLOTX1 : OFF_SLOTX0);
    int lane = threadIdx.x;
    for (int pass = 0; pass < 2; pass++) {
        int* slot = pass ? slotX : slotY;
        int base = 0;
        for (int p0 = 0; p0 < MV; p0 += 64) {
            int p = p0 + lane;
            int v = (p < MV) ? slot[(size_t)w * MV + p] : -1;
            bool occ = v >= 0;
            unsigned long long m = __ballot(occ);
            int rank = __popcll(m & ((1ull << lane) - 1ull));
            if (occ) slot[(size_t)w * MV + base + rank] = v;
            base += __popcll(m);
        }
    }
}

// ---------------- kernel 4: emit set_voxel_inds + mask (round-0 body, merged) --
__global__ void write_sets_both(const int* __restrict__ ws, float* __restrict__ outArea) {
    long long tid = (long long)blockIdx.x * blockDim.x + threadIdx.x;
    const long long T0 = 2LL * CAP_S0 * SET_SIZE;
    const long long T1 = 2LL * CAP_S1 * SET_SIZE;
    int shift = tid >= T0;
    long long t = shift ? tid - T0 : tid;
    if (shift && t >= T1) return;
    int cap = shift ? CAP_S1 : CAP_S0;
    int MV = shift ? MV1 : MV0;
    const int* setWin  = ws + (shift ? OFF_SETWIN1 : OFF_SETWIN0);
    const int* setBase = ws + (shift ? OFF_SETBASE1 : OFF_SETBASE0);
    const int* cnt     = ws + (shift ? OFF_CNT1 : OFF_CNT0);
    const int* slotY   = ws + (shift ? OFF_SLOTY1 : OFF_SLOTY0);
    const int* slotX   = ws + (shift ? OFF_SLOTX1 : OFF_SLOTX0);
    int S = ws[shift ? OFF_S1 : OFF_S0];
    int j = (int)(t % SET_SIZE);
    long long u = t / SET_SIZE;
    int q = (int)(u % cap);
    int branch = (int)(u / cap);
    if (branch >= 2 || q >= S) return;
    long long sOff = shift ? 4LL * SET_SIZE * (long long)ws[OFF_S0] : 0;
    int w = setWin[q];
    int i = q - setBase[w];
    int vnum = cnt[w];
    int setnum = (vnum + SET_SIZE - 1) / SET_SIZE;
    int den = setnum * SET_SIZE;
    int r  = ((i * SET_SIZE + j) * vnum) / den;              // DSVT Eq.3 spreading
    int rp = (j > 0) ? (((i * SET_SIZE + j - 1) * vnum) / den) : -1;
    const int* sorted = branch ? slotX : slotY;
    int vox = sorted[(size_t)w * MV + r];
    long long idx = (long long)branch * S * SET_SIZE + (long long)q * SET_SIZE + j;
    outArea[sOff + idx] = (float)vox;                                   // set_inds
    outArea[sOff + 2LL * S * SET_SIZE + idx] = (r == rp) ? 1.0f : 0.0f; // mask
}

// ---------------- kernel 5: pos-embed lookup table (round-0 form) --------------
// pos_embeds depend only on (k, cell); BN stats closed-form from integer moments.
__global__ void build_table(const float* __restrict__ w1, const float* __restrict__ gamma,
                            const float* __restrict__ beta, const float* __restrict__ w2,
                            const float* __restrict__ b2, const int* __restrict__ mom,
                            float* __restrict__ table, int N) {
    int k = blockIdx.x / MV1;          // 0..7
    int cell = blockIdx.x % MV1;       // 0..575
    int shift = k & 1;
    int wdim = shift ? 24 : 12;
    if (cell >= wdim * wdim) return;
    int j = threadIdx.x;               // 0..191
    const int* m = mom + shift * 5;
    double invN = 1.0 / (double)N;
    double mx = m[0] * invN, my = m[1] * invN;
    double vx = m[2] * invN - mx * mx;
    double vy = m[3] * invN - my * my;
    double cxy = m[4] * invN - mx * my;
    int cy = cell / wdim, cx = cell % wdim;
    double xx = (double)(cx - 6), yy = (double)(cy - 6);
    float w10 = w1[(k * 2 + 0) * DIM + j];
    float w11 = w1[(k * 2 + 1) * DIM + j];
    double var = (double)w10 * w10 * vx + (double)w11 * w11 * vy + 2.0 * (double)w10 * w11 * cxy;
    double rs = 1.0 / sqrt(var + 1e-5);
    double hn = ((xx - mx) * (double)w10 + (yy - my) * (double)w11) * rs * (double)gamma[k * DIM + j]
                + (double)beta[k * DIM + j];
    float hr = hn > 0.0 ? (float)hn : 0.0f;
    __shared__ float sh[DIM];
    sh[j] = hr;
    __syncthreads();
    float acc = b2[k * DIM + j];
    const float* w2k = w2 + (size_t)k * DIM * DIM;
    #pragma unroll 8
    for (int i = 0; i < DIM; i++) acc += sh[i] * w2k[i * DIM + j];
    table[((size_t)k * MV1 + cell) * DIM + j] = acc;
}

// ---------------- kernel 6: scatter pos_embeds + coords->float piggyback -------
__global__ void scatter_pe(const float4* __restrict__ table, const int* __restrict__ cell0,
                           const int* __restrict__ cell1, float4* __restrict__ outPe,
                           const int4* __restrict__ coords, float4* __restrict__ outCoords,
                           int N) {
    long long tid = (long long)blockIdx.x * blockDim.x + threadIdx.x;
    if (tid < N) {
        int4 c = coords[tid];
        outCoords[tid] = make_float4((float)c.x, (float)c.y, (float)c.z, (float)c.w);
    }
    long long total = 8LL * N * (DIM / 4);
    if (tid >= total) return;
    int q = (int)(tid % (DIM / 4));
    long long t = tid / (DIM / 4);
    int v = (int)(t % N);
    int k = (int)(t / N);
    int cell = (k & 1) ? cell1[v] : cell0[v];
    outPe[tid] = table[((size_t)k * MV1 + cell) * (DIM / 4) + q];
}

extern "C" void kernel_launch(void* const* d_in, const int* in_sizes, int n_in,
                              void* d_out, int out_size, void* d_ws, size_t ws_size,
                              hipStream_t stream) {
    const float* feat  = (const float*)d_in[0];
    const int* coords  = (const int*)d_in[1];
    const float* w1    = (const float*)d_in[2];
    // d_in[3] = pe_b1: cancels inside BN (h - mu), unused
    const float* gamma = (const float*)d_in[4];
    const float* beta  = (const float*)d_in[5];
    const float* w2    = (const float*)d_in[6];
    const float* b2    = (const float*)d_in[7];
    int N = in_sizes[1] / 4;   // 60000
    int* ws = (int*)d_ws;
    float* out = (float*)d_out;

    init_ws<<<(SLOT4 + 255) / 256, 256, 0, stream>>>(ws);

    voxel_pass<<<(N + 255) / 256, 256, 0, stream>>>((const int4*)coords, N, ws);

    scan_both<<<2, 256, 0, stream>>>(ws);

    compact_all<<<W0 + W1, 64, 0, stream>>>(ws);

    // output layout (floats): [feat N*192][coords N*4][inds0 2*S0*36][mask0 2*S0*36]
    //                         [inds1 2*S1*36][mask1 2*S1*36][pos_embeds 8*N*192]
    long long off2 = (long long)N * DIM + (long long)N * 4;
    {
        long long threads = 2LL * (CAP_S0 + CAP_S1) * SET_SIZE;
        write_sets_both<<<(int)((threads + 255) / 256), 256, 0, stream>>>(ws, out + off2);
    }

    build_table<<<8 * MV1, DIM, 0, stream>>>(w1, gamma, beta, w2, b2,
                                             ws + OFF_MOM, (float*)(ws + OFF_TABLE), N);

    long long off6 = (long long)out_size - 8LL * N * DIM;
    {
        long long t4 = 8LL * N * (DIM / 4);
        scatter_pe<<<(int)((t4 + 255) / 256), 256, 0, stream>>>(
            (const float4*)(ws + OFF_TABLE), ws + OFF_CELL0, ws + OFF_CELL1,
            (float4*)(out + off6), (const int4*)coords,
            (float4*)(out + (long long)N * DIM), N);
    }

    hipMemcpyAsync(out, feat, (size_t)N * DIM * sizeof(float), hipMemcpyDeviceToDevice, stream);
}